// Round 9
// baseline (290.424 us; speedup 1.0000x reference)
//
#include <hip/hip_runtime.h>
#include <math.h>

// ContextualLoss 3D: N=8, C=128, L=4096.
// R9: barrier-free K-loop — streamed B-fragments read DIRECTLY from global (L2-resident via
//     XCD grouping) into registers; no LDS tile, no __syncthreads in the hot loop. Fixed tile
//     register-cached as before. Grid 512 (2-way split). RACE FIX: cmP gets its own buffer
//     (R8 aliased cmP=rmP while k_colmax read rmP -> absmax 0.125).
// R4/R7 lesson (twice): never force 3 waves/SIMD. R6 win kept: XCD-grouped decode.

#define NB 8
#define CC 128
#define LL 4096
#define CL (CC * LL)
#define EPSV 1e-5f
#define L2E 1.44269504f
#define TWO_L2E 2.88539008f

typedef __bf16 bf16x8 __attribute__((ext_vector_type(8)));
typedef float f32x4 __attribute__((ext_vector_type(4)));

// f32 -> bf16 bits, round-nearest-even
__device__ __forceinline__ unsigned short f2bf(float f) {
    unsigned u = __float_as_uint(f);
    u += 0x7FFFu + ((u >> 16) & 1u);
    return (unsigned short)(u >> 16);
}

// ---------- mu stage 1: per-(n,c) sum of y[n][c][:] (1024 blocks, float4); also zero loss acc ----
__global__ void k_mu1(const float* __restrict__ y, float* __restrict__ muP, float* __restrict__ out) {
    const int b = blockIdx.x;            // n*128 + c
    const int t = threadIdx.x;
    if (b == 0 && t == 0) out[0] = 0.f;  // k_loss atomicAdds into this (stream-ordered)
    const float* p = y + (size_t)b * LL;
    float4 v0 = *(const float4*)(p + t * 4);
    float4 v1 = *(const float4*)(p + 1024 + t * 4);
    float4 v2 = *(const float4*)(p + 2048 + t * 4);
    float4 v3 = *(const float4*)(p + 3072 + t * 4);
    float s = (v0.x + v0.y + v0.z + v0.w) + (v1.x + v1.y + v1.z + v1.w)
            + (v2.x + v2.y + v2.z + v2.w) + (v3.x + v3.y + v3.z + v3.w);
    for (int o = 1; o < 64; o <<= 1) s += __shfl_xor(s, o, 64);
    __shared__ float red[4];
    if ((t & 63) == 0) red[t >> 6] = s;
    __syncthreads();
    if (t == 0) muP[b] = (red[0] + red[1]) + (red[2] + red[3]);
}

// ---------- prep: derive mu in-block, center, L2-normalize over c, emit bf16 [n][l][c] ----------
__global__ __launch_bounds__(256, 2) void k_prep(const float* __restrict__ x, const float* __restrict__ y,
                                                 const float* __restrict__ muP,
                                                 unsigned short* __restrict__ xt, unsigned short* __restrict__ yt) {
    __shared__ float tf[CC][132];  // [c][l] fp32 tile
    __shared__ float ssq[2][CC];
    __shared__ float invn[CC];
    __shared__ float mu_s[CC];
    const int b = blockIdx.x;  // 512
    const float* src = (b & 256) ? y : x;
    unsigned short* dst = (b & 256) ? yt : xt;
    const int sub = b & 255;
    const int n = sub >> 5, l0 = (sub & 31) << 7;
    const int t = threadIdx.x;
    if (t < CC) {   // mu[c] = sum_n muP[n][c] / (NB*LL)
        float s = 0.f;
#pragma unroll
        for (int nn = 0; nn < NB; ++nn) s += muP[nn * CC + t];
        mu_s[t] = s * (1.0f / (float)(NB * LL));
    }
    const float* g = src + (size_t)n * CL + l0;
#pragma unroll
    for (int it = 0; it < 16; ++it) {
        int id = (it << 8) + t;            // 4096 float4 chunks
        int c = id >> 5, l4 = (id & 31) << 2;
        *(float4*)&tf[c][l4] = *(const float4*)(g + (size_t)c * LL + l4);
    }
    __syncthreads();
    {   // center + sum-of-squares: thread -> (l, c-half)
        const int l = t & 127, half = t >> 7;
        float ss = 0.f;
#pragma unroll
        for (int cc = 0; cc < 64; ++cc) {
            int c = (half << 6) + cc;
            float v = tf[c][l] - mu_s[c];
            tf[c][l] = v;
            ss += v * v;
        }
        ssq[half][l] = ss;
    }
    __syncthreads();
    if (t < CC) invn[t] = 1.0f / fmaxf(sqrtf(ssq[0][t] + ssq[1][t]), 1e-12f);
    __syncthreads();
    unsigned short* o = dst + ((size_t)n * LL + l0) * CC;
#pragma unroll
    for (int it = 0; it < 8; ++it) {
        int id = (it << 8) + t;            // 2048 chunks of 8 bf16
        int lr = id >> 4, c8 = (id & 15) << 3;
        float w = invn[lr];
        unsigned short h[8] __attribute__((aligned(16)));
#pragma unroll
        for (int j = 0; j < 8; ++j) h[j] = f2bf(tf[c8 + j][lr] * w);
        *(uint4*)&o[(size_t)lr * CC + c8] = *(uint4*)h;
    }
}

// ---------- one-time gather of the fixed tile's fragments from global ----------
__device__ __forceinline__ void gather_frags(const unsigned short* __restrict__ g,  // tile base
                                             bf16x8 (&areg)[4][4], int row0, int lane) {
    const int mr = lane & 15, q = lane >> 4;
    const unsigned short* ab = g + ((size_t)(row0 + mr) << 7) + q * 8;
#pragma unroll
    for (int k0i = 0; k0i < 4; ++k0i)
#pragma unroll
        for (int i = 0; i < 4; ++i)
            areg[k0i][i] = *(const bf16x8*)(ab + ((size_t)(i * 16) << 7) + k0i * 32);
}

// Barrier-free MFMA on one streamed tile read straight from global (L2-hot).
// bp = tile base + ((col0 + mr) << 7) + q*8  (per-lane B-fragment base).
__device__ __forceinline__ void mfma_direct(const bf16x8 (&areg)[4][4],
                                            const unsigned short* __restrict__ bp,
                                            f32x4 (&acc)[4][4]) {
#pragma unroll
    for (int k0i = 0; k0i < 4; ++k0i) {
        bf16x8 bb[4];
#pragma unroll
        for (int j = 0; j < 4; ++j)
            bb[j] = *(const bf16x8*)(bp + ((size_t)(j * 16) << 7) + k0i * 32);
#pragma unroll
        for (int i = 0; i < 4; ++i)
#pragma unroll
            for (int j = 0; j < 4; ++j)
                acc[i][j] = __builtin_amdgcn_mfma_f32_16x16x32_bf16(areg[k0i][i], bb[j], acc[i][j], 0, 0, 0);
    }
}

// C/D layout (verified R2): value acc[i][j][r] -> row = row0+i*16+q*4+r, col = col0+j*16+(lane&15).

// XCD-grouped decode for grid 512: the 32 blocks sharing one (n, split) stream land on one
// XCD (round-robin dispatch) so the streamed tiles stay in that XCD's L2.
#define DECODE_512(b, n_, lt_, ms_)                        \
    const int xcd_ = (b) & 7, slot_ = (b) >> 3;            \
    const int grp_ = xcd_ * 2 + (slot_ >> 5);              \
    const int n_ = grp_ >> 1, ms_ = grp_ & 1, lt_ = slot_ & 31;

// ---------- pass 1: rowmax partials; fixed A = x-tile (regs), streamed B = y-tiles (global) ----
__global__ __launch_bounds__(256, 2) void k_rowmax(const unsigned short* __restrict__ xt,
                                                   const unsigned short* __restrict__ yt,
                                                   float* __restrict__ rmP) {
    DECODE_512(blockIdx.x, n, lt, ms)
    const int t = threadIdx.x, lane = t & 63, w = t >> 6;
    const int row0 = (w & 1) << 6, col0 = (w >> 1) << 6;
    const int mr = lane & 15, q = lane >> 4;
    bf16x8 areg[4][4];
    gather_frags(xt + ((size_t)(n * LL + lt * 128) << 7), areg, row0, lane);
    float rmax[16];
#pragma unroll
    for (int v = 0; v < 16; ++v) rmax[v] = -1e30f;
    const unsigned short* ybase = yt + ((size_t)(n * LL + col0 + mr) << 7) + q * 8;
    for (int mt = ms * 16; mt < ms * 16 + 16; ++mt) {
        const unsigned short* bp = ybase + ((size_t)(mt * 128) << 7);
        f32x4 acc[4][4];
#pragma unroll
        for (int i = 0; i < 4; ++i)
#pragma unroll
            for (int j = 0; j < 4; ++j) acc[i][j] = 0.f;
        mfma_direct(areg, bp, acc);
#pragma unroll
        for (int i = 0; i < 4; ++i)
#pragma unroll
            for (int r = 0; r < 4; ++r) {
                float m = acc[i][0][r];
#pragma unroll
                for (int j = 1; j < 4; ++j) m = fmaxf(m, acc[i][j][r]);
                rmax[i * 4 + r] = fmaxf(rmax[i * 4 + r], m);
            }
    }
#pragma unroll
    for (int v = 0; v < 16; ++v) {
        rmax[v] = fmaxf(rmax[v], __shfl_xor(rmax[v], 1, 64));
        rmax[v] = fmaxf(rmax[v], __shfl_xor(rmax[v], 2, 64));
        rmax[v] = fmaxf(rmax[v], __shfl_xor(rmax[v], 4, 64));
        rmax[v] = fmaxf(rmax[v], __shfl_xor(rmax[v], 8, 64));
    }
    if ((lane & 15) == 0) {
        const int part = ms * 2 + (w >> 1);  // 4 disjoint partials
#pragma unroll
        for (int v = 0; v < 16; ++v) {
            int row = lt * 128 + row0 + (v >> 2) * 16 + q * 4 + (v & 3);
            rmP[((size_t)part << 15) + n * LL + row] = rmax[v];
        }
    }
}

// ---------- pass 2: Z partials; b2 derived in-block from rmP (one barrier, then free-running) ----
__global__ __launch_bounds__(256, 2) void k_z(const unsigned short* __restrict__ xt,
                                              const unsigned short* __restrict__ yt,
                                              const float* __restrict__ rmP,
                                              float* __restrict__ Zp) {
    __shared__ float b2s[CC];
    DECODE_512(blockIdx.x, n, lt, ms)
    const int t = threadIdx.x, lane = t & 63, w = t >> 6;
    const int row0 = (w & 1) << 6, col0 = (w >> 1) << 6;
    const int mr = lane & 15, q = lane >> 4;
    if (t < CC) {  // b2 for this block's 128 rows
        size_t gi = (size_t)n * LL + lt * 128 + t;
        float rm = -1e30f;
#pragma unroll
        for (int p = 0; p < 4; ++p) rm = fmaxf(rm, rmP[gi + ((size_t)p << 15)]);
        b2s[t] = (2.0f / (1.0f - rm + EPSV)) * L2E;
    }
    bf16x8 areg[4][4];
    gather_frags(xt + ((size_t)(n * LL + lt * 128) << 7), areg, row0, lane);
    __syncthreads();
    float b2[16], zs[16];
#pragma unroll
    for (int v = 0; v < 16; ++v) {
        b2[v] = b2s[row0 + (v >> 2) * 16 + q * 4 + (v & 3)];
        zs[v] = 0.f;
    }
    const unsigned short* ybase = yt + ((size_t)(n * LL + col0 + mr) << 7) + q * 8;
    for (int mt = ms * 16; mt < ms * 16 + 16; ++mt) {
        const unsigned short* bp = ybase + ((size_t)(mt * 128) << 7);
        f32x4 acc[4][4];
#pragma unroll
        for (int i = 0; i < 4; ++i)
#pragma unroll
            for (int j = 0; j < 4; ++j) acc[i][j] = 0.f;
        mfma_direct(areg, bp, acc);
#pragma unroll
        for (int i = 0; i < 4; ++i)
#pragma unroll
            for (int r = 0; r < 4; ++r) {
                int v = i * 4 + r;
                float e2v = TWO_L2E - b2[v];
                float s = 0.f;
#pragma unroll
                for (int j = 0; j < 4; ++j)
                    s += __builtin_amdgcn_exp2f(fmaf(b2[v], acc[i][j][r], e2v));
                zs[v] += s;
            }
    }
#pragma unroll
    for (int v = 0; v < 16; ++v) {
        zs[v] += __shfl_xor(zs[v], 1, 64);
        zs[v] += __shfl_xor(zs[v], 2, 64);
        zs[v] += __shfl_xor(zs[v], 4, 64);
        zs[v] += __shfl_xor(zs[v], 8, 64);
    }
    if ((lane & 15) == 0) {
        const int part = ms * 2 + (w >> 1);
#pragma unroll
        for (int v = 0; v < 16; ++v) {
            int row = lt * 128 + row0 + (v >> 2) * 16 + q * 4 + (v & 3);
            Zp[((size_t)part << 15) + n * LL + row] = zs[v];
        }
    }
}

// ---------- pass 3: colmax partials; b2/g2 in-block from rmP/Zp; streamed x from global ----------
__global__ __launch_bounds__(256, 2) void k_colmax(const unsigned short* __restrict__ xt,
                                                   const unsigned short* __restrict__ yt,
                                                   const float* __restrict__ rmP, const float* __restrict__ Zp,
                                                   float* __restrict__ cmP) {
    __shared__ float b2s[2048], g2s[2048];
    DECODE_512(blockIdx.x, n, ct, ls)
    const int t = threadIdx.x, lane = t & 63, w = t >> 6;
    const int row0 = (w & 1) << 6, col0 = (w >> 1) << 6;
    const int mr = lane & 15, q = lane >> 4;
    // b2/g2 for this block's 2048 x-rows (ls*2048 .. +2047)
    for (int i = t; i < 2048; i += 256) {
        size_t gi = (size_t)n * LL + ls * 2048 + i;
        float rm = -1e30f;
#pragma unroll
        for (int p = 0; p < 4; ++p) rm = fmaxf(rm, rmP[gi + ((size_t)p << 15)]);
        float b2 = (2.0f / (1.0f - rm + EPSV)) * L2E;
        float Z = 0.f;
#pragma unroll
        for (int p = 0; p < 4; ++p) Z += Zp[gi + ((size_t)p << 15)];
        b2s[i] = b2;
        g2s[i] = (TWO_L2E - b2) - __builtin_amdgcn_logf(Z);
    }
    bf16x8 areg[4][4];
    gather_frags(yt + ((size_t)(n * LL + ct * 128) << 7), areg, row0, lane);
    __syncthreads();
    float cmax[16];
#pragma unroll
    for (int v = 0; v < 16; ++v) cmax[v] = -1e30f;
    const unsigned short* xbase = xt + ((size_t)(n * LL + col0 + mr) << 7) + q * 8;
    for (int lt = ls * 16; lt < ls * 16 + 16; ++lt) {
        const unsigned short* bp = xbase + ((size_t)(lt * 128) << 7);
        f32x4 acc[4][4];
#pragma unroll
        for (int i = 0; i < 4; ++i)
#pragma unroll
            for (int j = 0; j < 4; ++j) acc[i][j] = 0.f;
        mfma_direct(areg, bp, acc);
        float b2v[4], g2v[4];
        const int lbase = (lt - ls * 16) * 128 + col0 + mr;
#pragma unroll
        for (int j = 0; j < 4; ++j) {
            b2v[j] = b2s[lbase + j * 16];
            g2v[j] = g2s[lbase + j * 16];
        }
#pragma unroll
        for (int i = 0; i < 4; ++i)
#pragma unroll
            for (int r = 0; r < 4; ++r) {
                int v = i * 4 + r;
                float m = cmax[v];
#pragma unroll
                for (int j = 0; j < 4; ++j)
                    m = fmaxf(m, fmaf(b2v[j], acc[i][j][r], g2v[j]));
                cmax[v] = m;
            }
    }
#pragma unroll
    for (int v = 0; v < 16; ++v) {
        cmax[v] = fmaxf(cmax[v], __shfl_xor(cmax[v], 1, 64));
        cmax[v] = fmaxf(cmax[v], __shfl_xor(cmax[v], 2, 64));
        cmax[v] = fmaxf(cmax[v], __shfl_xor(cmax[v], 4, 64));
        cmax[v] = fmaxf(cmax[v], __shfl_xor(cmax[v], 8, 64));
    }
    if (mr == 0) {
        const int part = ls * 2 + (w >> 1);  // 4 disjoint partials
#pragma unroll
        for (int v = 0; v < 16; ++v) {
            int yc = ct * 128 + row0 + (v >> 2) * 16 + q * 4 + (v & 3);
            cmP[((size_t)part << 15) + n * LL + yc] = cmax[v];
        }
    }
}

// ---------- final loss: 8 blocks (one per n), atomicAdd the per-n term ----------
__global__ void k_loss(const float* __restrict__ cmP, float* __restrict__ out) {
    __shared__ float red[256];
    const int n = blockIdx.x, t = threadIdx.x;
    float s = 0.f;
    for (int m = t; m < LL; m += 256) {
        size_t idx = (size_t)n * LL + m;
        float e = -1e30f;
#pragma unroll
        for (int p = 0; p < 4; ++p) e = fmaxf(e, cmP[idx + ((size_t)p << 15)]);
        s += __builtin_amdgcn_exp2f(e);
    }
    red[t] = s;
    __syncthreads();
    for (int o = 128; o > 0; o >>= 1) {
        if (t < o) red[t] += red[t + o];
        __syncthreads();
    }
    if (t == 0)
        atomicAdd(out, -logf(red[0] * (1.0f / (float)LL) + EPSV) * (1.0f / (float)NB));
}

extern "C" void kernel_launch(void* const* d_in, const int* in_sizes, int n_in,
                              void* d_out, int out_size, void* d_ws, size_t ws_size,
                              hipStream_t stream) {
    const float* x = (const float*)d_in[0];
    const float* y = (const float*)d_in[1];
    float* out = (float*)d_out;
    char* ws = (char*)d_ws;

    unsigned short* xt = (unsigned short*)ws;                    // 8,388,608 B
    unsigned short* yt = (unsigned short*)(ws + 8388608);        // 8,388,608 B
    char* p = ws + 16777216;
    float* muP = (float*)p;            p += 4096;
    float* rmP = (float*)p;            p += 4 * 131072;
    float* Zp  = (float*)p;            p += 4 * 131072;
    float* cmP = (float*)p;            p += 4 * 131072;          // OWN buffer (R8 race fix)

    k_mu1<<<1024, 256, 0, stream>>>(y, muP, out);
    k_prep<<<512, 256, 0, stream>>>(x, y, muP, xt, yt);
    k_rowmax<<<512, 256, 0, stream>>>(xt, yt, rmP);
    k_z<<<512, 256, 0, stream>>>(xt, yt, rmP, Zp);
    k_colmax<<<512, 256, 0, stream>>>(xt, yt, rmP, Zp, cmP);
    k_loss<<<8, 256, 0, stream>>>(cmP, out);
}

// Round 10
// 209.369 us; speedup vs baseline: 1.3871x; 1.3871x over previous
//
#include <hip/hip_runtime.h>
#include <math.h>

// ContextualLoss 3D: N=8, C=128, L=4096.
// R10: software-pipelined K-loop — LDS double-buffer + raw s_barrier + manual
//      `s_waitcnt vmcnt(8)` (tile i retired, tile i+1 in flight during compute).
//      __syncthreads (which drains vmcnt(0)) removed from the hot loop entirely.
//      cmP has its own buffer (fixes R8 race). Grid 1024 + XCD decode kept (FETCH 8.4MB).
// Lessons: R4/R7 never cap VGPR below need (spill); R9 never drop LDS staging (L2 latency).

#define NB 8
#define CC 128
#define LL 4096
#define CL (CC * LL)
#define EPSV 1e-5f
#define L2E 1.44269504f
#define TWO_L2E 2.88539008f

typedef __bf16 bf16x8 __attribute__((ext_vector_type(8)));
typedef float f32x4 __attribute__((ext_vector_type(4)));

// f32 -> bf16 bits, round-nearest-even
__device__ __forceinline__ unsigned short f2bf(float f) {
    unsigned u = __float_as_uint(f);
    u += 0x7FFFu + ((u >> 16) & 1u);
    return (unsigned short)(u >> 16);
}

// ---------- mu stage 1: per-(n,c) sum of y[n][c][:] (1024 blocks); also zero loss acc ----------
__global__ void k_mu1(const float* __restrict__ y, float* __restrict__ muP, float* __restrict__ out) {
    const int b = blockIdx.x;            // n*128 + c
    const int t = threadIdx.x;
    if (b == 0 && t == 0) out[0] = 0.f;  // k_loss atomicAdds into this (stream-ordered)
    const float* p = y + (size_t)b * LL;
    float4 v0 = *(const float4*)(p + t * 4);
    float4 v1 = *(const float4*)(p + 1024 + t * 4);
    float4 v2 = *(const float4*)(p + 2048 + t * 4);
    float4 v3 = *(const float4*)(p + 3072 + t * 4);
    float s = (v0.x + v0.y + v0.z + v0.w) + (v1.x + v1.y + v1.z + v1.w)
            + (v2.x + v2.y + v2.z + v2.w) + (v3.x + v3.y + v3.z + v3.w);
    for (int o = 1; o < 64; o <<= 1) s += __shfl_xor(s, o, 64);
    __shared__ float red[4];
    if ((t & 63) == 0) red[t >> 6] = s;
    __syncthreads();
    if (t == 0) muP[b] = (red[0] + red[1]) + (red[2] + red[3]);
}

// ---------- prep: derive mu in-block, center, L2-normalize over c, emit bf16 [n][l][c] ----------
__global__ __launch_bounds__(256, 2) void k_prep(const float* __restrict__ x, const float* __restrict__ y,
                                                 const float* __restrict__ muP,
                                                 unsigned short* __restrict__ xt, unsigned short* __restrict__ yt) {
    __shared__ float tf[CC][132];  // [c][l] fp32 tile
    __shared__ float ssq[2][CC];
    __shared__ float invn[CC];
    __shared__ float mu_s[CC];
    const int b = blockIdx.x;  // 512
    const float* src = (b & 256) ? y : x;
    unsigned short* dst = (b & 256) ? yt : xt;
    const int sub = b & 255;
    const int n = sub >> 5, l0 = (sub & 31) << 7;
    const int t = threadIdx.x;
    if (t < CC) {   // mu[c] = sum_n muP[n][c] / (NB*LL)
        float s = 0.f;
#pragma unroll
        for (int nn = 0; nn < NB; ++nn) s += muP[nn * CC + t];
        mu_s[t] = s * (1.0f / (float)(NB * LL));
    }
    const float* g = src + (size_t)n * CL + l0;
#pragma unroll
    for (int it = 0; it < 16; ++it) {
        int id = (it << 8) + t;            // 4096 float4 chunks
        int c = id >> 5, l4 = (id & 31) << 2;
        *(float4*)&tf[c][l4] = *(const float4*)(g + (size_t)c * LL + l4);
    }
    __syncthreads();
    {   // center + sum-of-squares: thread -> (l, c-half)
        const int l = t & 127, half = t >> 7;
        float ss = 0.f;
#pragma unroll
        for (int cc = 0; cc < 64; ++cc) {
            int c = (half << 6) + cc;
            float v = tf[c][l] - mu_s[c];
            tf[c][l] = v;
            ss += v * v;
        }
        ssq[half][l] = ss;
    }
    __syncthreads();
    if (t < CC) invn[t] = 1.0f / fmaxf(sqrtf(ssq[0][t] + ssq[1][t]), 1e-12f);
    __syncthreads();
    unsigned short* o = dst + ((size_t)n * LL + l0) * CC;
#pragma unroll
    for (int it = 0; it < 8; ++it) {
        int id = (it << 8) + t;            // 2048 chunks of 8 bf16
        int lr = id >> 4, c8 = (id & 15) << 3;
        float w = invn[lr];
        unsigned short h[8] __attribute__((aligned(16)));
#pragma unroll
        for (int j = 0; j < 8; ++j) h[j] = f2bf(tf[c8 + j][lr] * w);
        *(uint4*)&o[(size_t)lr * CC + c8] = *(uint4*)h;
    }
}

// ---------- DMA-stage one 128x128 bf16 tile into unpadded LDS, XOR-granule swizzle ----------
// Per WAVE: 8 global_load_lds issues (its 32 rows). Per-wave vmcnt accounting relies on this.
__device__ __forceinline__ void stage_dma(const unsigned short* __restrict__ g,
                                          unsigned short* lds, int t) {
    const int w = t >> 6, ln = t & 63;
#pragma unroll
    for (int c = 0; c < 8; ++c) {
        int rbase = w * 32 + c * 4;
        int row = rbase + (ln >> 4);
        int gg = (ln & 15) ^ (row & 15);
        const unsigned short* gp = g + ((size_t)row << 7) + (gg << 3);
        __builtin_amdgcn_global_load_lds(
            (const __attribute__((address_space(1))) void*)gp,
            (__attribute__((address_space(3))) void*)(lds + (rbase << 7)),
            16, 0, 0);
    }
}

// swizzled fragment read: logical (row r, k-granule kq) -> LDS[r][kq ^ (r&15)]
__device__ __forceinline__ bf16x8 ldsfrag(const unsigned short* lds, int r, int kq) {
    return *(const bf16x8*)&lds[(r << 7) + ((kq ^ (r & 15)) << 3)];
}

// ---------- one-time gather of the fixed tile's fragments from global ----------
__device__ __forceinline__ void gather_frags(const unsigned short* __restrict__ g,  // tile base
                                             bf16x8 (&areg)[4][4], int row0, int lane) {
    const int mr = lane & 15, q = lane >> 4;
    const unsigned short* ab = g + ((size_t)(row0 + mr) << 7) + q * 8;
#pragma unroll
    for (int k0i = 0; k0i < 4; ++k0i)
#pragma unroll
        for (int i = 0; i < 4; ++i)
            areg[k0i][i] = *(const bf16x8*)(ab + ((size_t)(i * 16) << 7) + k0i * 32);
}

// MFMA on one streamed LDS tile: fixed frags in areg, streamed frags read swizzled.
__device__ __forceinline__ void mfma_stream(const bf16x8 (&areg)[4][4], const unsigned short* Bs,
                                            f32x4 (&acc)[4][4], int col0, int lane) {
    const int mr = lane & 15, q = lane >> 4;
#pragma unroll
    for (int k0i = 0; k0i < 4; ++k0i) {
        bf16x8 b[4];
#pragma unroll
        for (int j = 0; j < 4; ++j)
            b[j] = ldsfrag(Bs, col0 + j * 16 + mr, 4 * k0i + q);
#pragma unroll
        for (int i = 0; i < 4; ++i)
#pragma unroll
            for (int j = 0; j < 4; ++j)
                acc[i][j] = __builtin_amdgcn_mfma_f32_16x16x32_bf16(areg[k0i][i], b[j], acc[i][j], 0, 0, 0);
    }
}

// Pipeline sync: wait for the OLDEST 8 DMA issues (tile i) while the next 8 (tile i+1)
// stay in flight. Raw s_barrier has no implicit waitcnt drain (unlike __syncthreads).
#define PIPE_WAIT_BARRIER() do {                                   \
    asm volatile("s_waitcnt vmcnt(8)" ::: "memory");               \
    __builtin_amdgcn_s_barrier();                                  \
} while (0)
#define PIPE_RELEASE_BARRIER() do {                                \
    asm volatile("" ::: "memory");                                 \
    __builtin_amdgcn_s_barrier();                                  \
} while (0)

// C/D layout (verified R2): value acc[i][j][r] -> row = row0+i*16+q*4+r, col = col0+j*16+(lane&15).

// XCD-grouped decode for grid 1024: blocks sharing one (n, split) stream land on one XCD.
#define DECODE_B(b, n_, lt_, ms_)                          \
    const int xcd_ = (b) & 7, slot_ = (b) >> 3;            \
    const int grp_ = xcd_ * 4 + (slot_ >> 5);              \
    const int n_ = grp_ >> 2, ms_ = grp_ & 3, lt_ = slot_ & 31;

// ---------- pass 1: rowmax partials; pipelined dbuf K-loop ----------
__global__ __launch_bounds__(256, 2) void k_rowmax(const unsigned short* __restrict__ xt,
                                                   const unsigned short* __restrict__ yt,
                                                   float* __restrict__ rmP) {
    __shared__ unsigned short Bs[2][CC * CC];
    DECODE_B(blockIdx.x, n, lt, ms)
    const int t = threadIdx.x, lane = t & 63, w = t >> 6;
    const int row0 = (w & 1) << 6, col0 = (w >> 1) << 6;
    const int q = lane >> 4;
    const unsigned short* ytn = yt + ((size_t)n * LL << 7);
    bf16x8 areg[4][4];
    gather_frags(xt + ((size_t)(n * LL + lt * 128) << 7), areg, row0, lane);
    float rmax[16];
#pragma unroll
    for (int v = 0; v < 16; ++v) rmax[v] = -1e30f;
    const int mt0 = ms * 8;
    stage_dma(ytn + ((size_t)(mt0 * 128) << 7), Bs[0], t);
    stage_dma(ytn + ((size_t)((mt0 + 1) * 128) << 7), Bs[1], t);
    int pb = 0;
    for (int i = 0; i < 8; ++i) {
        PIPE_WAIT_BARRIER();
        f32x4 acc[4][4];
#pragma unroll
        for (int ii = 0; ii < 4; ++ii)
#pragma unroll
            for (int j = 0; j < 4; ++j) acc[ii][j] = 0.f;
        mfma_stream(areg, Bs[pb], acc, col0, lane);
#pragma unroll
        for (int ii = 0; ii < 4; ++ii)
#pragma unroll
            for (int r = 0; r < 4; ++r) {
                float m = acc[ii][0][r];
#pragma unroll
                for (int j = 1; j < 4; ++j) m = fmaxf(m, acc[ii][j][r]);
                rmax[ii * 4 + r] = fmaxf(rmax[ii * 4 + r], m);
            }
        PIPE_RELEASE_BARRIER();
        if (i + 2 < 8) stage_dma(ytn + ((size_t)((mt0 + i + 2) * 128) << 7), Bs[pb], t);
        pb ^= 1;
    }
#pragma unroll
    for (int v = 0; v < 16; ++v) {
        rmax[v] = fmaxf(rmax[v], __shfl_xor(rmax[v], 1, 64));
        rmax[v] = fmaxf(rmax[v], __shfl_xor(rmax[v], 2, 64));
        rmax[v] = fmaxf(rmax[v], __shfl_xor(rmax[v], 4, 64));
        rmax[v] = fmaxf(rmax[v], __shfl_xor(rmax[v], 8, 64));
    }
    if ((lane & 15) == 0) {
        const int part = ms * 2 + (w >> 1);  // 8 disjoint partials
#pragma unroll
        for (int v = 0; v < 16; ++v) {
            int row = lt * 128 + row0 + (v >> 2) * 16 + q * 4 + (v & 3);
            rmP[((size_t)part << 15) + n * LL + row] = rmax[v];
        }
    }
}

// ---------- pass 2: Z partials; b2 prolog + pipelined dbuf K-loop ----------
__global__ __launch_bounds__(256, 2) void k_z(const unsigned short* __restrict__ xt,
                                              const unsigned short* __restrict__ yt,
                                              const float* __restrict__ rmP,
                                              float* __restrict__ Zp) {
    __shared__ unsigned short Bs[2][CC * CC];
    __shared__ float b2s[CC];
    DECODE_B(blockIdx.x, n, lt, ms)
    const int t = threadIdx.x, lane = t & 63, w = t >> 6;
    const int row0 = (w & 1) << 6, col0 = (w >> 1) << 6;
    const int q = lane >> 4;
    if (t < CC) {  // b2 for this block's 128 rows
        size_t gi = (size_t)n * LL + lt * 128 + t;
        float rm = -1e30f;
#pragma unroll
        for (int p = 0; p < 8; ++p) rm = fmaxf(rm, rmP[gi + ((size_t)p << 15)]);
        b2s[t] = (2.0f / (1.0f - rm + EPSV)) * L2E;
    }
    bf16x8 areg[4][4];
    gather_frags(xt + ((size_t)(n * LL + lt * 128) << 7), areg, row0, lane);
    __syncthreads();  // b2s visible; drains the gather too (prologue DMA issued after)
    float b2[16], zs[16];
#pragma unroll
    for (int v = 0; v < 16; ++v) {
        b2[v] = b2s[row0 + (v >> 2) * 16 + q * 4 + (v & 3)];
        zs[v] = 0.f;
    }
    const unsigned short* ytn = yt + ((size_t)n * LL << 7);
    const int mt0 = ms * 8;
    stage_dma(ytn + ((size_t)(mt0 * 128) << 7), Bs[0], t);
    stage_dma(ytn + ((size_t)((mt0 + 1) * 128) << 7), Bs[1], t);
    int pb = 0;
    for (int i = 0; i < 8; ++i) {
        PIPE_WAIT_BARRIER();
        f32x4 acc[4][4];
#pragma unroll
        for (int ii = 0; ii < 4; ++ii)
#pragma unroll
            for (int j = 0; j < 4; ++j) acc[ii][j] = 0.f;
        mfma_stream(areg, Bs[pb], acc, col0, lane);
        PIPE_RELEASE_BARRIER();
        if (i + 2 < 8) stage_dma(ytn + ((size_t)((mt0 + i + 2) * 128) << 7), Bs[pb], t);
        pb ^= 1;
#pragma unroll
        for (int ii = 0; ii < 4; ++ii)
#pragma unroll
            for (int r = 0; r < 4; ++r) {
                int v = ii * 4 + r;
                float e2v = TWO_L2E - b2[v];
                float s = 0.f;
#pragma unroll
                for (int j = 0; j < 4; ++j)
                    s += __builtin_amdgcn_exp2f(fmaf(b2[v], acc[ii][j][r], e2v));
                zs[v] += s;
            }
    }
#pragma unroll
    for (int v = 0; v < 16; ++v) {
        zs[v] += __shfl_xor(zs[v], 1, 64);
        zs[v] += __shfl_xor(zs[v], 2, 64);
        zs[v] += __shfl_xor(zs[v], 4, 64);
        zs[v] += __shfl_xor(zs[v], 8, 64);
    }
    if ((lane & 15) == 0) {
        const int part = ms * 2 + (w >> 1);
#pragma unroll
        for (int v = 0; v < 16; ++v) {
            int row = lt * 128 + row0 + (v >> 2) * 16 + q * 4 + (v & 3);
            Zp[((size_t)part << 15) + n * LL + row] = zs[v];
        }
    }
}

// ---------- pass 3: colmax partials; b2/g2 prolog + pipelined dbuf K-loop ----------
__global__ __launch_bounds__(256, 2) void k_colmax(const unsigned short* __restrict__ xt,
                                                   const unsigned short* __restrict__ yt,
                                                   const float* __restrict__ rmP, const float* __restrict__ Zp,
                                                   float* __restrict__ cmP) {
    __shared__ unsigned short Bs[2][CC * CC];
    __shared__ float b2s[1024], g2s[1024];
    DECODE_B(blockIdx.x, n, ct, ls)
    const int t = threadIdx.x, lane = t & 63, w = t >> 6;
    const int row0 = (w & 1) << 6, col0 = (w >> 1) << 6;
    const int mr = lane & 15, q = lane >> 4;
    // b2/g2 for this block's 1024 x-rows (ls*1024 .. +1023)
    for (int i = t; i < 1024; i += 256) {
        size_t gi = (size_t)n * LL + ls * 1024 + i;
        float rm = -1e30f;
#pragma unroll
        for (int p = 0; p < 8; ++p) rm = fmaxf(rm, rmP[gi + ((size_t)p << 15)]);
        float b2 = (2.0f / (1.0f - rm + EPSV)) * L2E;
        float Z = 0.f;
#pragma unroll
        for (int p = 0; p < 8; ++p) Z += Zp[gi + ((size_t)p << 15)];
        b2s[i] = b2;
        g2s[i] = (TWO_L2E - b2) - __builtin_amdgcn_logf(Z);
    }
    bf16x8 areg[4][4];
    gather_frags(yt + ((size_t)(n * LL + ct * 128) << 7), areg, row0, lane);
    __syncthreads();  // b2s/g2s visible; prologue DMA after
    float cmax[16];
#pragma unroll
    for (int v = 0; v < 16; ++v) cmax[v] = -1e30f;
    const unsigned short* xtn = xt + ((size_t)n * LL << 7);
    const int lt0 = ls * 8;
    stage_dma(xtn + ((size_t)(lt0 * 128) << 7), Bs[0], t);
    stage_dma(xtn + ((size_t)((lt0 + 1) * 128) << 7), Bs[1], t);
    int pb = 0;
    for (int i = 0; i < 8; ++i) {
        PIPE_WAIT_BARRIER();
        f32x4 acc[4][4];
#pragma unroll
        for (int ii = 0; ii < 4; ++ii)
#pragma unroll
            for (int j = 0; j < 4; ++j) acc[ii][j] = 0.f;
        mfma_stream(areg, Bs[pb], acc, col0, lane);
        PIPE_RELEASE_BARRIER();
        if (i + 2 < 8) stage_dma(xtn + ((size_t)((lt0 + i + 2) * 128) << 7), Bs[pb], t);
        pb ^= 1;
        float b2v[4], g2v[4];
        const int lbase = i * 128 + col0 + mr;
#pragma unroll
        for (int j = 0; j < 4; ++j) {
            b2v[j] = b2s[lbase + j * 16];
            g2v[j] = g2s[lbase + j * 16];
        }
#pragma unroll
        for (int ii = 0; ii < 4; ++ii)
#pragma unroll
            for (int r = 0; r < 4; ++r) {
                int v = ii * 4 + r;
                float m = cmax[v];
#pragma unroll
                for (int j = 0; j < 4; ++j)
                    m = fmaxf(m, fmaf(b2v[j], acc[ii][j][r], g2v[j]));
                cmax[v] = m;
            }
    }
#pragma unroll
    for (int v = 0; v < 16; ++v) {
        cmax[v] = fmaxf(cmax[v], __shfl_xor(cmax[v], 1, 64));
        cmax[v] = fmaxf(cmax[v], __shfl_xor(cmax[v], 2, 64));
        cmax[v] = fmaxf(cmax[v], __shfl_xor(cmax[v], 4, 64));
        cmax[v] = fmaxf(cmax[v], __shfl_xor(cmax[v], 8, 64));
    }
    if (mr == 0) {
        const int part = ls * 2 + (w >> 1);  // 8 disjoint partials
#pragma unroll
        for (int v = 0; v < 16; ++v) {
            int yc = ct * 128 + row0 + (v >> 2) * 16 + q * 4 + (v & 3);
            cmP[((size_t)part << 15) + n * LL + yc] = cmax[v];
        }
    }
}

// ---------- final loss: 8 blocks (one per n), atomicAdd the per-n term ----------
__global__ void k_loss(const float* __restrict__ cmP, float* __restrict__ out) {
    __shared__ float red[256];
    const int n = blockIdx.x, t = threadIdx.x;
    float s = 0.f;
    for (int m = t; m < LL; m += 256) {
        size_t idx = (size_t)n * LL + m;
        float e = -1e30f;
#pragma unroll
        for (int p = 0; p < 8; ++p) e = fmaxf(e, cmP[idx + ((size_t)p << 15)]);
        s += __builtin_amdgcn_exp2f(e);
    }
    red[t] = s;
    __syncthreads();
    for (int o = 128; o > 0; o >>= 1) {
        if (t < o) red[t] += red[t + o];
        __syncthreads();
    }
    if (t == 0)
        atomicAdd(out, -logf(red[0] * (1.0f / (float)LL) + EPSV) * (1.0f / (float)NB));
}

extern "C" void kernel_launch(void* const* d_in, const int* in_sizes, int n_in,
                              void* d_out, int out_size, void* d_ws, size_t ws_size,
                              hipStream_t stream) {
    const float* x = (const float*)d_in[0];
    const float* y = (const float*)d_in[1];
    float* out = (float*)d_out;
    char* ws = (char*)d_ws;

    unsigned short* xt = (unsigned short*)ws;                    // 8,388,608 B
    unsigned short* yt = (unsigned short*)(ws + 8388608);        // 8,388,608 B
    char* p = ws + 16777216;
    float* muP = (float*)p;            p += 4096;
    float* rmP = (float*)p;            p += 8 * 131072;
    float* Zp  = (float*)p;            p += 8 * 131072;
    float* cmP = (float*)p;            p += 8 * 131072;          // OWN buffer (R8 race fix)

    k_mu1<<<1024, 256, 0, stream>>>(y, muP, out);
    k_prep<<<512, 256, 0, stream>>>(x, y, muP, xt, yt);
    k_rowmax<<<1024, 256, 0, stream>>>(xt, yt, rmP);
    k_z<<<1024, 256, 0, stream>>>(xt, yt, rmP, Zp);
    k_colmax<<<1024, 256, 0, stream>>>(xt, yt, rmP, Zp, cmP);
    k_loss<<<8, 256, 0, stream>>>(cmP, out);
}

// Round 11
// 191.935 us; speedup vs baseline: 1.5131x; 1.0908x over previous
//
#include <hip/hip_runtime.h>
#include <math.h>

// ContextualLoss 3D: N=8, C=128, L=4096.
// R11: occupancy via genuinely smaller live-set — wave tile 32x64 (acc 32 AGPR + areg 32 VGPR,
//      was 64+64), 4 waves cover 128 rows, streamed 64-col tile (16KB LDS). launch_bounds(256,3)
//      cap (~168) >= live need (~130): spill-safe per R4 rule. Waves own disjoint rows -> 4 partials.
// Lessons: R4/R7 cap<need spills; R9 no-LDS loses to L2 latency; R5/R10 pipelining neutral at 2 waves.

#define NB 8
#define CC 128
#define LL 4096
#define CL (CC * LL)
#define EPSV 1e-5f
#define L2E 1.44269504f
#define TWO_L2E 2.88539008f

typedef __bf16 bf16x8 __attribute__((ext_vector_type(8)));
typedef float f32x4 __attribute__((ext_vector_type(4)));

// f32 -> bf16 bits, round-nearest-even
__device__ __forceinline__ unsigned short f2bf(float f) {
    unsigned u = __float_as_uint(f);
    u += 0x7FFFu + ((u >> 16) & 1u);
    return (unsigned short)(u >> 16);
}

// ---------- mu stage 1: per-(n,c) sum of y[n][c][:] (1024 blocks); also zero loss acc ----------
__global__ void k_mu1(const float* __restrict__ y, float* __restrict__ muP, float* __restrict__ out) {
    const int b = blockIdx.x;            // n*128 + c
    const int t = threadIdx.x;
    if (b == 0 && t == 0) out[0] = 0.f;  // k_loss atomicAdds into this (stream-ordered)
    const float* p = y + (size_t)b * LL;
    float4 v0 = *(const float4*)(p + t * 4);
    float4 v1 = *(const float4*)(p + 1024 + t * 4);
    float4 v2 = *(const float4*)(p + 2048 + t * 4);
    float4 v3 = *(const float4*)(p + 3072 + t * 4);
    float s = (v0.x + v0.y + v0.z + v0.w) + (v1.x + v1.y + v1.z + v1.w)
            + (v2.x + v2.y + v2.z + v2.w) + (v3.x + v3.y + v3.z + v3.w);
    for (int o = 1; o < 64; o <<= 1) s += __shfl_xor(s, o, 64);
    __shared__ float red[4];
    if ((t & 63) == 0) red[t >> 6] = s;
    __syncthreads();
    if (t == 0) muP[b] = (red[0] + red[1]) + (red[2] + red[3]);
}

// ---------- prep: derive mu in-block, center, L2-normalize over c, emit bf16 [n][l][c] ----------
__global__ __launch_bounds__(256, 2) void k_prep(const float* __restrict__ x, const float* __restrict__ y,
                                                 const float* __restrict__ muP,
                                                 unsigned short* __restrict__ xt, unsigned short* __restrict__ yt) {
    __shared__ float tf[CC][132];  // [c][l] fp32 tile
    __shared__ float ssq[2][CC];
    __shared__ float invn[CC];
    __shared__ float mu_s[CC];
    const int b = blockIdx.x;  // 512
    const float* src = (b & 256) ? y : x;
    unsigned short* dst = (b & 256) ? yt : xt;
    const int sub = b & 255;
    const int n = sub >> 5, l0 = (sub & 31) << 7;
    const int t = threadIdx.x;
    if (t < CC) {   // mu[c] = sum_n muP[n][c] / (NB*LL)
        float s = 0.f;
#pragma unroll
        for (int nn = 0; nn < NB; ++nn) s += muP[nn * CC + t];
        mu_s[t] = s * (1.0f / (float)(NB * LL));
    }
    const float* g = src + (size_t)n * CL + l0;
#pragma unroll
    for (int it = 0; it < 16; ++it) {
        int id = (it << 8) + t;            // 4096 float4 chunks
        int c = id >> 5, l4 = (id & 31) << 2;
        *(float4*)&tf[c][l4] = *(const float4*)(g + (size_t)c * LL + l4);
    }
    __syncthreads();
    {   // center + sum-of-squares: thread -> (l, c-half)
        const int l = t & 127, half = t >> 7;
        float ss = 0.f;
#pragma unroll
        for (int cc = 0; cc < 64; ++cc) {
            int c = (half << 6) + cc;
            float v = tf[c][l] - mu_s[c];
            tf[c][l] = v;
            ss += v * v;
        }
        ssq[half][l] = ss;
    }
    __syncthreads();
    if (t < CC) invn[t] = 1.0f / fmaxf(sqrtf(ssq[0][t] + ssq[1][t]), 1e-12f);
    __syncthreads();
    unsigned short* o = dst + ((size_t)n * LL + l0) * CC;
#pragma unroll
    for (int it = 0; it < 8; ++it) {
        int id = (it << 8) + t;            // 2048 chunks of 8 bf16
        int lr = id >> 4, c8 = (id & 15) << 3;
        float w = invn[lr];
        unsigned short h[8] __attribute__((aligned(16)));
#pragma unroll
        for (int j = 0; j < 8; ++j) h[j] = f2bf(tf[c8 + j][lr] * w);
        *(uint4*)&o[(size_t)lr * CC + c8] = *(uint4*)h;
    }
}

// ---------- DMA-stage one 64(row)x128(K) bf16 tile into LDS, XOR-granule swizzle ----------
// Wave w stages rows w*16..w*16+15 (4 global_load_lds issues per thread).
__device__ __forceinline__ void stage_dma64(const unsigned short* __restrict__ g,
                                            unsigned short* lds, int t) {
    const int w = t >> 6, ln = t & 63;
#pragma unroll
    for (int c = 0; c < 4; ++c) {
        int rbase = w * 16 + c * 4;
        int row = rbase + (ln >> 4);
        int gg = (ln & 15) ^ (row & 15);
        const unsigned short* gp = g + ((size_t)row << 7) + (gg << 3);
        __builtin_amdgcn_global_load_lds(
            (const __attribute__((address_space(1))) void*)gp,
            (__attribute__((address_space(3))) void*)(lds + (rbase << 7)),
            16, 0, 0);
    }
}

// swizzled fragment read: logical (row r, k-granule kq) -> LDS[r][kq ^ (r&15)]
__device__ __forceinline__ bf16x8 ldsfrag(const unsigned short* lds, int r, int kq) {
    return *(const bf16x8*)&lds[(r << 7) + ((kq ^ (r & 15)) << 3)];
}

// ---------- one-time gather of the fixed tile's fragments (32 rows per wave) ----------
__device__ __forceinline__ void gather_frags32(const unsigned short* __restrict__ g,  // tile base
                                               bf16x8 (&areg)[4][2], int row0, int lane) {
    const int mr = lane & 15, q = lane >> 4;
    const unsigned short* ab = g + ((size_t)(row0 + mr) << 7) + q * 8;
#pragma unroll
    for (int k0i = 0; k0i < 4; ++k0i)
#pragma unroll
        for (int i = 0; i < 2; ++i)
            areg[k0i][i] = *(const bf16x8*)(ab + ((size_t)(i * 16) << 7) + k0i * 32);
}

// MFMA: 32 rows (regs) x 64 streamed cols (LDS tile), K=128.
__device__ __forceinline__ void mfma_stream32(const bf16x8 (&areg)[4][2], const unsigned short* Bs,
                                              f32x4 (&acc)[2][4], int lane) {
    const int mr = lane & 15, q = lane >> 4;
#pragma unroll
    for (int k0i = 0; k0i < 4; ++k0i) {
        bf16x8 b[4];
#pragma unroll
        for (int j = 0; j < 4; ++j)
            b[j] = ldsfrag(Bs, j * 16 + mr, 4 * k0i + q);
#pragma unroll
        for (int i = 0; i < 2; ++i)
#pragma unroll
            for (int j = 0; j < 4; ++j)
                acc[i][j] = __builtin_amdgcn_mfma_f32_16x16x32_bf16(areg[k0i][i], b[j], acc[i][j], 0, 0, 0);
    }
}

// C/D layout (verified R2): value acc[i][j][r] -> row = row0+i*16+q*4+r, col = j*16+(lane&15).

// XCD-grouped decode for grid 1024 (R6 win): blocks sharing one (n, split) stream -> one XCD.
#define DECODE_B(b, n_, lt_, ms_)                          \
    const int xcd_ = (b) & 7, slot_ = (b) >> 3;            \
    const int grp_ = xcd_ * 4 + (slot_ >> 5);              \
    const int n_ = grp_ >> 2, ms_ = grp_ & 3, lt_ = slot_ & 31;

// ---------- pass 1: rowmax partials; fixed A = x rows (regs), streamed 64-col y tiles ----------
__global__ __launch_bounds__(256, 3) void k_rowmax(const unsigned short* __restrict__ xt,
                                                   const unsigned short* __restrict__ yt,
                                                   float* __restrict__ rmP) {
    __shared__ unsigned short Bs[64 * CC];
    DECODE_B(blockIdx.x, n, lt, ms)
    const int t = threadIdx.x, lane = t & 63, w = t >> 6;
    const int row0 = w << 5;
    const int mr = lane & 15, q = lane >> 4;
    bf16x8 areg[4][2];
    gather_frags32(xt + ((size_t)(n * LL + lt * 128) << 7) + ((size_t)row0 << 7) - ((size_t)row0 << 7),
                   areg, row0, lane);
    float rmax[8];
#pragma unroll
    for (int v = 0; v < 8; ++v) rmax[v] = -1e30f;
    for (int mt = ms * 16; mt < ms * 16 + 16; ++mt) {
        __syncthreads();
        stage_dma64(yt + ((size_t)(n * LL + mt * 64) << 7), Bs, t);
        __syncthreads();
        f32x4 acc[2][4];
#pragma unroll
        for (int i = 0; i < 2; ++i)
#pragma unroll
            for (int j = 0; j < 4; ++j) acc[i][j] = 0.f;
        mfma_stream32(areg, Bs, acc, lane);
#pragma unroll
        for (int i = 0; i < 2; ++i)
#pragma unroll
            for (int r = 0; r < 4; ++r) {
                float m = acc[i][0][r];
#pragma unroll
                for (int j = 1; j < 4; ++j) m = fmaxf(m, acc[i][j][r]);
                rmax[i * 4 + r] = fmaxf(rmax[i * 4 + r], m);
            }
    }
#pragma unroll
    for (int v = 0; v < 8; ++v) {
        rmax[v] = fmaxf(rmax[v], __shfl_xor(rmax[v], 1, 64));
        rmax[v] = fmaxf(rmax[v], __shfl_xor(rmax[v], 2, 64));
        rmax[v] = fmaxf(rmax[v], __shfl_xor(rmax[v], 4, 64));
        rmax[v] = fmaxf(rmax[v], __shfl_xor(rmax[v], 8, 64));
    }
    if (mr == 0) {  // waves own disjoint rows -> partial index is just ms (4 partials)
#pragma unroll
        for (int v = 0; v < 8; ++v) {
            int row = lt * 128 + row0 + (v >> 2) * 16 + q * 4 + (v & 3);
            rmP[((size_t)ms << 15) + n * LL + row] = rmax[v];
        }
    }
}

// ---------- pass 2: Z partials; b2 prolog from rmP; streamed 64-col y tiles ----------
__global__ __launch_bounds__(256, 3) void k_z(const unsigned short* __restrict__ xt,
                                              const unsigned short* __restrict__ yt,
                                              const float* __restrict__ rmP,
                                              float* __restrict__ Zp) {
    __shared__ unsigned short Bs[64 * CC];
    __shared__ float b2s[CC];
    DECODE_B(blockIdx.x, n, lt, ms)
    const int t = threadIdx.x, lane = t & 63, w = t >> 6;
    const int row0 = w << 5;
    const int mr = lane & 15, q = lane >> 4;
    if (t < CC) {  // b2 for this block's 128 rows
        size_t gi = (size_t)n * LL + lt * 128 + t;
        float rm = -1e30f;
#pragma unroll
        for (int p = 0; p < 4; ++p) rm = fmaxf(rm, rmP[gi + ((size_t)p << 15)]);
        b2s[t] = (2.0f / (1.0f - rm + EPSV)) * L2E;
    }
    bf16x8 areg[4][2];
    gather_frags32(xt + ((size_t)(n * LL + lt * 128) << 7), areg, row0, lane);
    __syncthreads();
    float b2[8], zs[8];
#pragma unroll
    for (int v = 0; v < 8; ++v) {
        b2[v] = b2s[row0 + (v >> 2) * 16 + q * 4 + (v & 3)];
        zs[v] = 0.f;
    }
    for (int mt = ms * 16; mt < ms * 16 + 16; ++mt) {
        __syncthreads();
        stage_dma64(yt + ((size_t)(n * LL + mt * 64) << 7), Bs, t);
        __syncthreads();
        f32x4 acc[2][4];
#pragma unroll
        for (int i = 0; i < 2; ++i)
#pragma unroll
            for (int j = 0; j < 4; ++j) acc[i][j] = 0.f;
        mfma_stream32(areg, Bs, acc, lane);
#pragma unroll
        for (int i = 0; i < 2; ++i)
#pragma unroll
            for (int r = 0; r < 4; ++r) {
                int v = i * 4 + r;
                float e2v = TWO_L2E - b2[v];
                float s = 0.f;
#pragma unroll
                for (int j = 0; j < 4; ++j)
                    s += __builtin_amdgcn_exp2f(fmaf(b2[v], acc[i][j][r], e2v));
                zs[v] += s;
            }
    }
#pragma unroll
    for (int v = 0; v < 8; ++v) {
        zs[v] += __shfl_xor(zs[v], 1, 64);
        zs[v] += __shfl_xor(zs[v], 2, 64);
        zs[v] += __shfl_xor(zs[v], 4, 64);
        zs[v] += __shfl_xor(zs[v], 8, 64);
    }
    if (mr == 0) {
#pragma unroll
        for (int v = 0; v < 8; ++v) {
            int row = lt * 128 + row0 + (v >> 2) * 16 + q * 4 + (v & 3);
            Zp[((size_t)ms << 15) + n * LL + row] = zs[v];
        }
    }
}

// ---------- pass 3: colmax partials; fixed A = y-cols (regs), streamed 64-row x tiles ----------
__global__ __launch_bounds__(256, 3) void k_colmax(const unsigned short* __restrict__ xt,
                                                   const unsigned short* __restrict__ yt,
                                                   const float* __restrict__ rmP, const float* __restrict__ Zp,
                                                   float* __restrict__ cmP) {
    __shared__ unsigned short Bs[64 * CC];
    __shared__ float b2s[1024], g2s[1024];
    DECODE_B(blockIdx.x, n, ct, ls)
    const int t = threadIdx.x, lane = t & 63, w = t >> 6;
    const int row0 = w << 5;
    const int mr = lane & 15, q = lane >> 4;
    // b2/g2 for this block's 1024 streamed x-rows (ls*1024 .. +1023)
    for (int i = t; i < 1024; i += 256) {
        size_t gi = (size_t)n * LL + ls * 1024 + i;
        float rm = -1e30f;
#pragma unroll
        for (int p = 0; p < 4; ++p) rm = fmaxf(rm, rmP[gi + ((size_t)p << 15)]);
        float b2 = (2.0f / (1.0f - rm + EPSV)) * L2E;
        float Z = 0.f;
#pragma unroll
        for (int p = 0; p < 4; ++p) Z += Zp[gi + ((size_t)p << 15)];
        b2s[i] = b2;
        g2s[i] = (TWO_L2E - b2) - __builtin_amdgcn_logf(Z);
    }
    bf16x8 areg[4][2];
    gather_frags32(yt + ((size_t)(n * LL + ct * 128) << 7), areg, row0, lane);
    __syncthreads();
    float cmax[8];
#pragma unroll
    for (int v = 0; v < 8; ++v) cmax[v] = -1e30f;
    for (int lt = ls * 16; lt < ls * 16 + 16; ++lt) {
        __syncthreads();
        stage_dma64(xt + ((size_t)(n * LL + lt * 64) << 7), Bs, t);
        __syncthreads();
        f32x4 acc[2][4];
#pragma unroll
        for (int i = 0; i < 2; ++i)
#pragma unroll
            for (int j = 0; j < 4; ++j) acc[i][j] = 0.f;
        mfma_stream32(areg, Bs, acc, lane);
        float b2v[4], g2v[4];
        const int lbase = (lt - ls * 16) * 64 + mr;
#pragma unroll
        for (int j = 0; j < 4; ++j) {
            b2v[j] = b2s[lbase + j * 16];
            g2v[j] = g2s[lbase + j * 16];
        }
#pragma unroll
        for (int i = 0; i < 2; ++i)
#pragma unroll
            for (int r = 0; r < 4; ++r) {
                int v = i * 4 + r;
                float m = cmax[v];
#pragma unroll
                for (int j = 0; j < 4; ++j)
                    m = fmaxf(m, fmaf(b2v[j], acc[i][j][r], g2v[j]));
                cmax[v] = m;
            }
    }
#pragma unroll
    for (int v = 0; v < 8; ++v) {
        cmax[v] = fmaxf(cmax[v], __shfl_xor(cmax[v], 1, 64));
        cmax[v] = fmaxf(cmax[v], __shfl_xor(cmax[v], 2, 64));
        cmax[v] = fmaxf(cmax[v], __shfl_xor(cmax[v], 4, 64));
        cmax[v] = fmaxf(cmax[v], __shfl_xor(cmax[v], 8, 64));
    }
    if (mr == 0) {
#pragma unroll
        for (int v = 0; v < 8; ++v) {
            int yc = ct * 128 + row0 + (v >> 2) * 16 + q * 4 + (v & 3);
            cmP[((size_t)ls << 15) + n * LL + yc] = cmax[v];
        }
    }
}

// ---------- final loss: 8 blocks (one per n), atomicAdd the per-n term ----------
__global__ void k_loss(const float* __restrict__ cmP, float* __restrict__ out) {
    __shared__ float red[256];
    const int n = blockIdx.x, t = threadIdx.x;
    float s = 0.f;
    for (int m = t; m < LL; m += 256) {
        size_t idx = (size_t)n * LL + m;
        float e = -1e30f;
#pragma unroll
        for (int p = 0; p < 4; ++p) e = fmaxf(e, cmP[idx + ((size_t)p << 15)]);
        s += __builtin_amdgcn_exp2f(e);
    }
    red[t] = s;
    __syncthreads();
    for (int o = 128; o > 0; o >>= 1) {
        if (t < o) red[t] += red[t + o];
        __syncthreads();
    }
    if (t == 0)
        atomicAdd(out, -logf(red[0] * (1.0f / (float)LL) + EPSV) * (1.0f / (float)NB));
}

extern "C" void kernel_launch(void* const* d_in, const int* in_sizes, int n_in,
                              void* d_out, int out_size, void* d_ws, size_t ws_size,
                              hipStream_t stream) {
    const float* x = (const float*)d_in[0];
    const float* y = (const float*)d_in[1];
    float* out = (float*)d_out;
    char* ws = (char*)d_ws;

    unsigned short* xt = (unsigned short*)ws;                    // 8,388,608 B
    unsigned short* yt = (unsigned short*)(ws + 8388608);        // 8,388,608 B
    char* p = ws + 16777216;
    float* muP = (float*)p;            p += 4096;
    float* rmP = (float*)p;            p += 4 * 131072;
    float* Zp  = (float*)p;            p += 4 * 131072;
    float* cmP = (float*)p;            p += 4 * 131072;          // own buffer (R8 race lesson)

    k_mu1<<<1024, 256, 0, stream>>>(y, muP, out);
    k_prep<<<512, 256, 0, stream>>>(x, y, muP, xt, yt);
    k_rowmax<<<1024, 256, 0, stream>>>(xt, yt, rmP);
    k_z<<<1024, 256, 0, stream>>>(xt, yt, rmP, Zp);
    k_colmax<<<1024, 256, 0, stream>>>(xt, yt, rmP, Zp, cmP);
    k_loss<<<8, 256, 0, stream>>>(cmP, out);
}